// Round 2
// baseline (664.969 us; speedup 1.0000x reference)
//
#include <hip/hip_runtime.h>
#include <math.h>

// Model dims
#define CB 128   // batch
#define CN 5     // n_vars
#define CL 128   // seq len
#define CS 8     // patch size
#define CP 16    // n_patches
#define CD 64    // d_hidden
#define CDT 16   // d_time
#define CDIN 17  // DT+1
#define CNF 63   // D-1
#define CNC 39   // n_classes

__device__ __forceinline__ float wave_sum(float v) {
    v += __shfl_xor(v, 32);
    v += __shfl_xor(v, 16);
    v += __shfl_xor(v, 8);
    v += __shfl_xor(v, 4);
    v += __shfl_xor(v, 2);
    v += __shfl_xor(v, 1);
    return v;
}

// ---------------------------------------------------------------------------
// prep: weight transposes. filter/out-channel becomes the fastest (lane) dim
// so all per-wave weight reads are coalesced 256B segments.
// ---------------------------------------------------------------------------
__global__ void prep_kernel(const float* __restrict__ mf_w1, const float* __restrict__ mf_w2,
                            const float* __restrict__ mf_b2, const float* __restrict__ fp_w,
                            const float* __restrict__ attn_in_w, const float* __restrict__ attn_out_w,
                            const float* __restrict__ ffn_w1, const float* __restrict__ ffn_w2,
                            float* __restrict__ w1c16, float* __restrict__ w2t, float* __restrict__ b2t,
                            float* __restrict__ fp_wt, float* __restrict__ wit, float* __restrict__ wot,
                            float* __restrict__ fw1t, float* __restrict__ fw2t) {
    int idx = blockIdx.x * 256 + threadIdx.x;
    if (idx < 17 * 17 * 64) {          // w2t[(k*17+j)*64+f] = w2[f][k][j]
        int f = idx & 63;
        int rc = idx >> 6;
        int k = rc / 17, j = rc % 17;
        w2t[idx] = (f < CNF) ? mf_w2[(f * 17 + k) * 17 + j] : 0.f;
    }
    if (idx < 17 * 64) {               // b2t[k*64+f] = b2[f][k]; w1c16[j*64+f] = w1[f][j][16]
        int f = idx & 63, r = idx >> 6;
        b2t[idx]   = (f < CNF) ? mf_b2[f * 17 + r] : 0.f;
        w1c16[idx] = (f < CNF) ? mf_w1[(f * 17 + r) * 17 + 16] : 0.f;
    }
    if (idx < 1024 * 64) {             // fp_wt[j*64+d] = fp_w[d][j]
        int d = idx & 63, j = idx >> 6;
        fp_wt[idx] = fp_w[d * 1024 + j];
    }
    if (idx < 2 * 64 * 192) {          // wit[bk][d*192+oc] = wi[bk][oc][d]
        int bk = idx / 12288, rem = idx % 12288;
        int d = rem / 192, oc = rem % 192;
        wit[idx] = attn_in_w[bk * 12288 + oc * 64 + d];
    }
    if (idx < 2 * 64 * 64) {           // wot[bk][c*64+d] = wo[bk][d][c]
        int bk = idx / 4096, rem = idx % 4096;
        int c = rem >> 6, d = rem & 63;
        wot[idx] = attn_out_w[bk * 4096 + d * 64 + c];
    }
    if (idx < 2 * 64 * 128) {          // fw1t[bk][d*128+c] = fw1[bk][c][d]
        int bk = idx / 8192, rem = idx % 8192;
        int d = rem / 128, c = rem % 128;
        fw1t[idx] = ffn_w1[bk * 8192 + c * 64 + d];
    }
    if (idx < 2 * 128 * 64) {          // fw2t[bk][c*64+d] = fw2[bk][d][c]
        int bk = idx / 8192, rem = idx % 8192;
        int c = rem >> 6, d = rem & 63;
        fw2t[idx] = ffn_w2[bk * 8192 + d * 128 + c];
    }
}

// ---------------------------------------------------------------------------
// prep2: t_rel is batch-invariant (arange(L)), so the te-part of TTCN phase A
// is shared by ALL B*N tokens. Precompute for the 16*8 distinct (p,s):
//   base[((p*8+s)*17+j)*64+f] = b1[f][j] + sum_{i<16} te[p,s,i]*w1[f][j][i]
//   te_tab[(p*8+s)*16+k] = te[p,s,k]
// One block per (p,s,j); lane = f.
// ---------------------------------------------------------------------------
__global__ __launch_bounds__(64) void prep2_kernel(
    const float* __restrict__ t_rel, const float* __restrict__ omega, const float* __restrict__ alpha,
    const float* __restrict__ mf_w1, const float* __restrict__ mf_b1,
    float* __restrict__ base, float* __restrict__ te_tab) {
    const int blk = blockIdx.x;               // = (p*8+s)*17 + j
    const int j = blk % 17;
    const int ps = blk / 17;                  // p*8+s
    const int p = ps >> 3, s = ps & 7;
    const int f = threadIdx.x;

    const float t = t_rel[p * CS + s];        // row b=0
    float te[16];
#pragma unroll
    for (int i = 0; i < 16; ++i)
        te[i] = (i == 0) ? (omega[0] * t + alpha[0]) : sinf(omega[i] * t + alpha[i]);

    float acc = 0.f;
    if (f < CNF) {
        acc = mf_b1[f * 17 + j];
        const float* w = mf_w1 + (f * 17 + j) * 17;
#pragma unroll
        for (int i = 0; i < 16; ++i) acc = fmaf(te[i], w[i], acc);
    }
    base[blk * 64 + f] = acc;

    if (j == 0 && f < 16) te_tab[ps * 16 + f] = te[f];
}

// ---------------------------------------------------------------------------
// TTCN v2: one wave per token; lane = filter f.
//   h[s][j] = relu(base[p,s,j,f] + v[s]*w1c16[j,f])   (computed on the fly)
//   lg[k][s] (+= h*w2) accumulated j-outer in 136 registers
//   softmax over s per k, out = sum_k sum_s sm*z[s][k]
// ---------------------------------------------------------------------------
__global__ __launch_bounds__(64) void ttcn_kernel(
    const float* __restrict__ x, const float* __restrict__ base,
    const float* __restrict__ te_tab, const float* __restrict__ w1c16,
    const float* __restrict__ w2t, const float* __restrict__ b2t,
    const float* __restrict__ pos_enc, float* __restrict__ hout) {
    __shared__ float zsh[8][17];   // z[s][k]: te for k<16, v for k==16
    const int tok = blockIdx.x;            // (b*5+n)*16+p
    const int p = tok & 15;
    const int lane = threadIdx.x;

    for (int e = lane; e < 8 * 17; e += 64) {
        int s = e / 17, k = e % 17;
        zsh[s][k] = (k < 16) ? te_tab[(p * 8 + s) * 16 + k] : x[tok * 8 + s];
    }
    __syncthreads();

    float lg[17][8];
#pragma unroll
    for (int k = 0; k < 17; ++k) {
        float bb = b2t[k * 64 + lane];
#pragma unroll
        for (int s = 0; s < 8; ++s) lg[k][s] = bb;
    }
    float v_s[8];
#pragma unroll
    for (int s = 0; s < 8; ++s) v_s[s] = zsh[s][16];

    const float* bp_ = base + p * 8 * 17 * 64;
#pragma unroll 1
    for (int j = 0; j < 17; ++j) {
        float w1c = w1c16[j * 64 + lane];
        float h_s[8];
#pragma unroll
        for (int s = 0; s < 8; ++s)
            h_s[s] = fmaxf(fmaf(v_s[s], w1c, bp_[(s * 17 + j) * 64 + lane]), 0.f);
#pragma unroll
        for (int k = 0; k < 17; ++k) {
            float wv = w2t[(k * 17 + j) * 64 + lane];
#pragma unroll
            for (int s = 0; s < 8; ++s) lg[k][s] = fmaf(h_s[s], wv, lg[k][s]);
        }
    }

    float out = 0.f;
#pragma unroll
    for (int k = 0; k < 17; ++k) {
        float m = lg[k][0];
#pragma unroll
        for (int s = 1; s < 8; ++s) m = fmaxf(m, lg[k][s]);
        float l = 0.f, o = 0.f;
#pragma unroll
        for (int s = 0; s < 8; ++s) {
            float e = __expf(lg[k][s] - m);
            l += e;
            o = fmaf(e, zsh[s][k], o);
        }
        out += o / l;
    }

    float val = (lane < CNF) ? out : 1.0f;
    hout[tok * 64 + lane] = val + pos_enc[p * 64 + lane];
}

// ---------------------------------------------------------------------------
// Intra-series transformer block: one 256-thread block per (b,n) row.
// All weight reads coalesced (transposed layouts); activations via LDS broadcast.
// ---------------------------------------------------------------------------
__global__ __launch_bounds__(256) void intra_kernel(
    float* __restrict__ h,
    const float* __restrict__ wit, const float* __restrict__ bi,
    const float* __restrict__ wot, const float* __restrict__ bo,
    const float* __restrict__ g1, const float* __restrict__ be1,
    const float* __restrict__ fw1t, const float* __restrict__ fb1,
    const float* __restrict__ fw2t, const float* __restrict__ fb2,
    const float* __restrict__ g2, const float* __restrict__ be2) {
    __shared__ float xs[16][64];
    __shared__ float qs[16][64];
    __shared__ float ks[16][64];
    __shared__ float vs[16][64];
    __shared__ float sc[4][16][16];
    __shared__ float os[16][64];
    __shared__ float x1[16][64];
    __shared__ float fs[16][128];

    const int row = blockIdx.x;  // b*5+n
    float* xin = h + row * CP * CD;
    const int t = threadIdx.x;

    for (int e = t; e < 1024; e += 256) xs[e >> 6][e & 63] = xin[e];
    __syncthreads();

    // qkv: lane = out channel oc (192 active); xs broadcast, wit coalesced
    if (t < 192) {
        const int oc = t;
        float acc[16];
#pragma unroll
        for (int p = 0; p < 16; ++p) acc[p] = bi[oc];
        for (int d = 0; d < 64; ++d) {
            float w = wit[d * 192 + oc];
#pragma unroll
            for (int p = 0; p < 16; ++p) acc[p] = fmaf(xs[p][d], w, acc[p]);
        }
#pragma unroll
        for (int p = 0; p < 16; ++p) {
            if (oc < 64)       qs[p][oc] = acc[p];
            else if (oc < 128) ks[p][oc - 64] = acc[p];
            else               vs[p][oc - 128] = acc[p];
        }
    }
    __syncthreads();

    // scores (4 heads x 16 x 16)
    for (int e = t; e < 1024; e += 256) {
        int hh = e >> 8, i = (e >> 4) & 15, j = e & 15;
        float acc = 0.f;
        for (int d = 0; d < 16; ++d) acc = fmaf(qs[i][hh * 16 + d], ks[j][hh * 16 + d], acc);
        sc[hh][i][j] = acc * 0.25f;  // 1/sqrt(16)
    }
    __syncthreads();

    // softmax over j per (head,i)
    if (t < 64) {
        int hh = t >> 4, i = t & 15;
        float m = sc[hh][i][0];
#pragma unroll
        for (int j = 1; j < 16; ++j) m = fmaxf(m, sc[hh][i][j]);
        float e_[16];
        float l = 0.f;
#pragma unroll
        for (int j = 0; j < 16; ++j) { e_[j] = __expf(sc[hh][i][j] - m); l += e_[j]; }
        float inv = 1.f / l;
#pragma unroll
        for (int j = 0; j < 16; ++j) sc[hh][i][j] = e_[j] * inv;
    }
    __syncthreads();

    // attn out
    for (int e = t; e < 1024; e += 256) {
        int p = e >> 6, c = e & 63, hh = c >> 4;
        float acc = 0.f;
        for (int j = 0; j < 16; ++j) acc = fmaf(sc[hh][p][j], vs[j][c], acc);
        os[p][c] = acc;
    }
    __syncthreads();

    // proj + residual (wot coalesced, os broadcast)
    for (int e = t; e < 1024; e += 256) {
        int p = e >> 6, d = e & 63;
        float acc = bo[d];
        for (int c = 0; c < 64; ++c) acc = fmaf(os[p][c], wot[c * 64 + d], acc);
        x1[p][d] = acc + xs[p][d];
    }
    __syncthreads();

    // LN1
    {
        int w = t >> 6, lane = t & 63;
        for (int p = w; p < 16; p += 4) {
            float v = x1[p][lane];
            float mu = wave_sum(v) * (1.f / 64);
            float d = v - mu;
            float var = wave_sum(d * d) * (1.f / 64);
            x1[p][lane] = d * rsqrtf(var + 1e-5f) * g1[lane] + be1[lane];
        }
    }
    __syncthreads();

    // FFN1
    for (int e = t; e < 2048; e += 256) {
        int p = e >> 7, c = e & 127;
        float acc = fb1[c];
        for (int d = 0; d < 64; ++d) acc = fmaf(x1[p][d], fw1t[d * 128 + c], acc);
        fs[p][c] = fmaxf(acc, 0.f);
    }
    __syncthreads();

    // FFN2 + residual
    for (int e = t; e < 1024; e += 256) {
        int p = e >> 6, d = e & 63;
        float acc = fb2[d];
        for (int c = 0; c < 128; ++c) acc = fmaf(fs[p][c], fw2t[c * 64 + d], acc);
        os[p][d] = acc + x1[p][d];
    }
    __syncthreads();

    // LN2 + write back
    {
        int w = t >> 6, lane = t & 63;
        for (int p = w; p < 16; p += 4) {
            float v = os[p][lane];
            float mu = wave_sum(v) * (1.f / 64);
            float d = v - mu;
            float var = wave_sum(d * d) * (1.f / 64);
            xin[p * 64 + lane] = d * rsqrtf(var + 1e-5f) * g2[lane] + be2[lane];
        }
    }
}

// ---------------------------------------------------------------------------
// Inter-series GSL + GNN: one 320-thread (5-wave) block per (b,p).
// wave = variable n, lane = channel d.
// ---------------------------------------------------------------------------
__global__ __launch_bounds__(320) void gnn_kernel(
    float* __restrict__ h,
    const float* __restrict__ Es1, const float* __restrict__ Es2,
    const float* __restrict__ Wd1, const float* __restrict__ bd1,
    const float* __restrict__ Wd2, const float* __restrict__ bd2,
    const float* __restrict__ Wg1, const float* __restrict__ bg1,
    const float* __restrict__ Wg2, const float* __restrict__ bg2,
    const float* __restrict__ gW, const float* __restrict__ gb,
    const float* __restrict__ g3, const float* __restrict__ be3) {
    __shared__ float hs[5][64];
    __shared__ float ep1[5][16], ep2[5][16];
    __shared__ float Araw[5][8], As[5][8], A2s[5][8];
    __shared__ float t1s[5][64], t2s[5][64];

    const int bp = blockIdx.x;
    const int b = bp >> 4, p = bp & 15;
    const int n = threadIdx.x >> 6, lane = threadIdx.x & 63;
    float* hptr = h + (((b * CN + n) * CP + p) * CD);

    hs[n][lane] = hptr[lane];
    __syncthreads();

    // Ed (lane<16 keeps its own row in registers)
    float a1 = 0.f, a2 = 0.f;
    if (lane < 16) {
        a1 = bd1[lane]; a2 = bd2[lane];
        for (int d = 0; d < 64; ++d) {
            a1 = fmaf(hs[n][d], Wd1[lane * 64 + d], a1);
            a2 = fmaf(hs[n][d], Wd2[lane * 64 + d], a2);
        }
    }
    // gates: relu(tanh([hh|Es] @ Wg.T + bg)) via full-wave reduction
    float p1 = hs[n][lane] * Wg1[lane] + ((lane < 16) ? Es1[n * 16 + lane] * Wg1[64 + lane] : 0.f);
    float p2 = hs[n][lane] * Wg2[lane] + ((lane < 16) ? Es2[n * 16 + lane] * Wg2[64 + lane] : 0.f);
    float gg1 = fmaxf(tanhf(wave_sum(p1) + bg1[0]), 0.f);
    float gg2 = fmaxf(tanhf(wave_sum(p2) + bg2[0]), 0.f);
    if (lane < 16) {
        ep1[n][lane] = Es1[n * 16 + lane] + gg1 * a1;
        ep2[n][lane] = Es2[n * 16 + lane] + gg2 * a2;
    }
    __syncthreads();

    // A = softmax(relu(Ep1 @ Ep2^T), axis=-1)
    if (lane < 5) {
        float e = 0.f;
#pragma unroll
        for (int k = 0; k < 16; ++k) e = fmaf(ep1[n][k], ep2[lane][k], e);
        Araw[n][lane] = fmaxf(e, 0.f);
    }
    __syncthreads();
    if (lane < 5) {
        float m = Araw[n][0];
#pragma unroll
        for (int j = 1; j < 5; ++j) m = fmaxf(m, Araw[n][j]);
        float l = 0.f;
#pragma unroll
        for (int j = 0; j < 5; ++j) l += __expf(Araw[n][j] - m);
        As[n][lane] = __expf(Araw[n][lane] - m) / l;
    }
    __syncthreads();
    if (lane < 5) {
        float a = 0.f;
#pragma unroll
        for (int l2 = 0; l2 < 5; ++l2) a = fmaf(As[n][l2], As[l2][lane], a);
        A2s[n][lane] = a;
    }
    __syncthreads();

    // t1 = A@hh, t2 = A^2@hh
    {
        float t1 = 0.f, t2 = 0.f;
#pragma unroll
        for (int m = 0; m < 5; ++m) {
            t1 = fmaf(As[n][m], hs[m][lane], t1);
            t2 = fmaf(A2s[n][m], hs[m][lane], t2);
        }
        t1s[n][lane] = t1;
        t2s[n][lane] = t2;
    }
    __syncthreads();

    // res = hh@gW0.T + t1@gW1.T + t2@gW2.T + (gb0+gb1+gb2)
    float res = gb[lane] + gb[64 + lane] + gb[128 + lane];
    for (int c = 0; c < 64; ++c) {
        res = fmaf(hs[n][c], gW[lane * 64 + c], res);
        res = fmaf(t1s[n][c], gW[4096 + lane * 64 + c], res);
        res = fmaf(t2s[n][c], gW[8192 + lane * 64 + c], res);
    }
    float pre = hs[n][lane] + fmaxf(res, 0.f);

    // LN3 + write back
    float mu = wave_sum(pre) * (1.f / 64);
    float d = pre - mu;
    float var = wave_sum(d * d) * (1.f / 64);
    hptr[lane] = d * rsqrtf(var + 1e-5f) * g3[lane] + be3[lane];
}

// ---------------------------------------------------------------------------
// Head: flat projection + q-embed concat + 3-layer per-variable MLP.
// one 64-thread block per (b,n); 4 independent acc chains on the 1024-dot.
// ---------------------------------------------------------------------------
__global__ __launch_bounds__(64) void head_kernel(
    const float* __restrict__ h, const float* __restrict__ fp_wt, const float* __restrict__ fp_b,
    const float* __restrict__ q_omega, const float* __restrict__ q_alpha,
    const float* __restrict__ ow1, const float* __restrict__ ob1,
    const float* __restrict__ ow2, const float* __restrict__ ob2,
    const float* __restrict__ ow3, const float* __restrict__ ob3,
    float* __restrict__ out) {
    __shared__ float flat[1024];
    __shared__ float inp[80];
    __shared__ float h1s[64], h2s[64];
    const int row = blockIdx.x;  // b*5+n
    const int n = row % CN;
    const int lane = threadIdx.x;
    const float* src = h + row * CP * CD;

    for (int e = lane; e < 1024; e += 64) flat[e] = src[e];
    __syncthreads();

    float a0 = 0.f, a1 = 0.f, a2 = 0.f, a3 = 0.f;
    for (int j = 0; j < 1024; j += 4) {
        a0 = fmaf(flat[j],     fp_wt[(j    ) * 64 + lane], a0);
        a1 = fmaf(flat[j + 1], fp_wt[(j + 1) * 64 + lane], a1);
        a2 = fmaf(flat[j + 2], fp_wt[(j + 2) * 64 + lane], a2);
        a3 = fmaf(flat[j + 3], fp_wt[(j + 3) * 64 + lane], a3);
    }
    inp[lane] = fp_b[lane] + ((a0 + a1) + (a2 + a3));
    if (lane < 16) {
        const float t = (float)CL;
        inp[64 + lane] = (lane == 0) ? (q_omega[0] * t + q_alpha[0])
                                     : sinf(q_omega[lane] * t + q_alpha[lane]);
    }
    __syncthreads();

    {
        float a = ob1[n * 64 + lane];
        const float* w = ow1 + (n * 64 + lane) * 80;
        for (int i = 0; i < 80; ++i) a = fmaf(inp[i], w[i], a);
        h1s[lane] = fmaxf(a, 0.f);
    }
    __syncthreads();
    {
        float a = ob2[n * 64 + lane];
        const float* w = ow2 + (n * 64 + lane) * 64;
        for (int i = 0; i < 64; ++i) a = fmaf(h1s[i], w[i], a);
        h2s[lane] = fmaxf(a, 0.f);
    }
    __syncthreads();
    if (lane < CNC) {
        float a = ob3[n * CNC + lane];
        const float* w = ow3 + (n * CNC + lane) * 64;
        for (int i = 0; i < 64; ++i) a = fmaf(h2s[i], w[i], a);
        out[row * CNC + lane] = a;
    }
}

// ---------------------------------------------------------------------------
extern "C" void kernel_launch(void* const* d_in, const int* in_sizes, int n_in,
                              void* d_out, int out_size, void* d_ws, size_t ws_size,
                              hipStream_t stream) {
    const float* x         = (const float*)d_in[0];
    const float* t_rel     = (const float*)d_in[1];
    const float* te_omega  = (const float*)d_in[2];
    const float* te_alpha  = (const float*)d_in[3];
    const float* mf_w1     = (const float*)d_in[4];
    const float* mf_b1     = (const float*)d_in[5];
    const float* mf_w2     = (const float*)d_in[6];
    const float* mf_b2     = (const float*)d_in[7];
    const float* pos_enc   = (const float*)d_in[8];
    const float* attn_in_w = (const float*)d_in[9];
    const float* attn_in_b = (const float*)d_in[10];
    const float* attn_out_w= (const float*)d_in[11];
    const float* attn_out_b= (const float*)d_in[12];
    const float* ln1_g     = (const float*)d_in[13];
    const float* ln1_b     = (const float*)d_in[14];
    const float* ffn_w1    = (const float*)d_in[15];
    const float* ffn_b1    = (const float*)d_in[16];
    const float* ffn_w2    = (const float*)d_in[17];
    const float* ffn_b2    = (const float*)d_in[18];
    const float* ln2_g     = (const float*)d_in[19];
    const float* ln2_b     = (const float*)d_in[20];
    const float* gsl_Es1   = (const float*)d_in[21];
    const float* gsl_Es2   = (const float*)d_in[22];
    const float* gsl_Wd1   = (const float*)d_in[23];
    const float* gsl_bd1   = (const float*)d_in[24];
    const float* gsl_Wd2   = (const float*)d_in[25];
    const float* gsl_bd2   = (const float*)d_in[26];
    const float* gsl_Wg1   = (const float*)d_in[27];
    const float* gsl_bg1   = (const float*)d_in[28];
    const float* gsl_Wg2   = (const float*)d_in[29];
    const float* gsl_bg2   = (const float*)d_in[30];
    const float* gnn_W     = (const float*)d_in[31];
    const float* gnn_b     = (const float*)d_in[32];
    const float* ln3_g     = (const float*)d_in[33];
    const float* ln3_b     = (const float*)d_in[34];
    const float* fp_w      = (const float*)d_in[35];
    const float* fp_b      = (const float*)d_in[36];
    const float* q_omega   = (const float*)d_in[37];
    const float* q_alpha   = (const float*)d_in[38];
    const float* ow1       = (const float*)d_in[39];
    const float* ob1       = (const float*)d_in[40];
    const float* ow2       = (const float*)d_in[41];
    const float* ob2       = (const float*)d_in[42];
    const float* ow3       = (const float*)d_in[43];
    const float* ob3       = (const float*)d_in[44];

    float* ws = (float*)d_ws;
    float* hbuf   = ws;                     // 128*5*16*64 = 655360
    float* base   = hbuf + 655360;          // 16*8*17*64 = 139264
    float* te_tab = base + 139264;          // 16*8*16    = 2048
    float* w1c16  = te_tab + 2048;          // 17*64      = 1088
    float* w2t    = w1c16 + 1088;           // 17*17*64   = 18496
    float* b2t    = w2t + 18496;            // 17*64      = 1088
    float* fp_wt  = b2t + 1088;             // 1024*64    = 65536
    float* wit    = fp_wt + 65536;          // 2*64*192   = 24576
    float* wot    = wit + 24576;            // 2*64*64    = 8192
    float* fw1t   = wot + 8192;             // 2*64*128   = 16384
    float* fw2t   = fw1t + 16384;           // 2*128*64   = 16384

    prep_kernel<<<256, 256, 0, stream>>>(mf_w1, mf_w2, mf_b2, fp_w,
                                         attn_in_w, attn_out_w, ffn_w1, ffn_w2,
                                         w1c16, w2t, b2t, fp_wt, wit, wot, fw1t, fw2t);

    prep2_kernel<<<CP * CS * CDIN, 64, 0, stream>>>(t_rel, te_omega, te_alpha,
                                                    mf_w1, mf_b1, base, te_tab);

    ttcn_kernel<<<CB * CN * CP, 64, 0, stream>>>(x, base, te_tab, w1c16,
                                                 w2t, b2t, pos_enc, hbuf);

    for (int bk = 0; bk < 2; ++bk) {
        intra_kernel<<<CB * CN, 256, 0, stream>>>(
            hbuf,
            wit + bk * 12288, attn_in_b + bk * 192,
            wot + bk * 4096, attn_out_b + bk * 64,
            ln1_g + bk * 64, ln1_b + bk * 64,
            fw1t + bk * 8192, ffn_b1 + bk * 128,
            fw2t + bk * 8192, ffn_b2 + bk * 64,
            ln2_g + bk * 64, ln2_b + bk * 64);

        gnn_kernel<<<CB * CP, 320, 0, stream>>>(
            hbuf,
            gsl_Es1 + bk * CN * 16, gsl_Es2 + bk * CN * 16,
            gsl_Wd1 + bk * 16 * 64, gsl_bd1 + bk * 16,
            gsl_Wd2 + bk * 16 * 64, gsl_bd2 + bk * 16,
            gsl_Wg1 + bk * 80, gsl_bg1 + bk,
            gsl_Wg2 + bk * 80, gsl_bg2 + bk,
            gnn_W + bk * 3 * 64 * 64, gnn_b + bk * 3 * 64,
            ln3_g + bk * 64, ln3_b + bk * 64);
    }

    head_kernel<<<CB * CN, 64, 0, stream>>>(hbuf, fp_wt, fp_b, q_omega, q_alpha,
                                            ow1, ob1, ow2, ob2, ow3, ob3,
                                            (float*)d_out);
}